// Round 4
// baseline (95.472 us; speedup 1.0000x reference)
//
#include <hip/hip_runtime.h>

#define NHID 25
#define NSTEP 20
#define DT_ (1.0/60.0)
#define EPS_ 1e-4
#define PQ_ 5.0
#define QV_ 200.0
#define QA_ 1.0

// ---------------------------------------------------------------------------
// Setup (1 block, 64 threads = 1 wave). Closed forms (HW-verified R2/R3):
//   u = Q0*Af, alpha = Af^T Q0 Af
//   Qf[r][c] = (2QA+EPS)delta + 2dt^2 sum_{rr>=max} w_rr((rr-r)(rr-c)alpha+QV)
//   phi[r] = sum_{rr>=r} w_rr (rr-r)
//   rho[r] = sum_{rr>=r} w_rr ((rr+1)(rr-r)alpha + QV)
//   [z1 z2] = Qf^{-1} [phi rho]    (register Gauss-Jordan, lane r owns row r)
//   bvec[k] = -2dt sum_{c<=k} z1[c](hdt2+(k-c)dt^2)
//   gvec[k] = (k+1)dt - 2dt sum_{c<=k} z2[c](hdt2+(k-c)dt^2)
// R3 lesson: per-block fused GJ serialized shfl->fma at ~120cyc each (VGPR=72
// proves the compiler interleaved to save registers). Here: GJ runs ONCE, and
// sched_barrier(0) pins the shfl batch so latency is paid once per pivot,
// not once per element. Phases A/C use per-lane LDS reads (no serial shfls).
// C layout (float): [0..24]=u, [32..51]=bvec, [64..83]=gvec.
// ---------------------------------------------------------------------------
__global__ __launch_bounds__(64) void setup_kernel(
    const float* __restrict__ Af, const float* __restrict__ Lq,
    float* __restrict__ C)
{
    __shared__ float  Afs[NHID];
    __shared__ double wv_[NHID];
    __shared__ double uv_[NHID];
    __shared__ double alpha_s;
    __shared__ double zs[2][NSTEP];

    const int t = threadIdx.x;
    const double dt = DT_;

    if (t < NHID) Afs[t] = Af[t];
    __syncthreads();

    // Phase A (per-lane LDS/global reads, loads pipeline, no cross-lane chains)
    if (t < NHID) {                       // w = Lq^T Af
        double acc = 0.0;
        for (int i = t; i < NHID; ++i)
            acc += (double)Lq[i * NHID + t] * (double)Afs[i];
        wv_[t] = acc;
    }
    __syncthreads();
    if (t < NHID) {                       // u = Lq w + eps*Af
        double acc = EPS_ * (double)Afs[t];
        for (int j = 0; j <= t; ++j)
            acc += (double)Lq[t * NHID + j] * wv_[j];
        uv_[t] = acc;
    }
    __syncthreads();
    if (t == 0) {                         // alpha = Af . u
        double a = 0.0;
        for (int i = 0; i < NHID; ++i) a += (double)Afs[i] * uv_[i];
        alpha_s = a;
    }
    __syncthreads();
    const double alpha = alpha_s;

    // Phase B: lane r (t<20) builds [Qf[r][*] | phi[r] | rho[r]] (per-lane f64)
    double row[NSTEP + 2];
    #pragma unroll
    for (int c = 0; c < NSTEP; ++c) {
        int m0 = (t > c) ? t : c;         // lanes >=20: empty -> 0
        double s = 0.0;
        for (int rr = m0; rr < NSTEP; ++rr) {
            double wr = (rr == NSTEP - 1) ? PQ_ : 1.0;
            s += wr * ((double)(rr - t) * (double)(rr - c) * alpha + QV_);
        }
        row[c] = 2.0 * dt * dt * s + ((t == c) ? (2.0 * QA_ + EPS_) : 0.0);
    }
    {
        double s20 = 0.0, s21 = 0.0;
        for (int rr = t; rr < NSTEP; ++rr) {
            double wr = (rr == NSTEP - 1) ? PQ_ : 1.0;
            s20 += wr * (double)(rr - t);
            s21 += wr * ((double)(rr + 1) * (double)(rr - t) * alpha + QV_);
        }
        row[NSTEP]     = s20;
        row[NSTEP + 1] = s21;
    }

    // Gauss-Jordan: batch pivot-row shuffles, PIN the batch with sched_barrier
    // so the 2x22 ds_bpermute issue back-to-back (one latency drain per pivot).
    #pragma unroll
    for (int piv = 0; piv < NSTEP; ++piv) {
        double pr[NSTEP + 2];
        #pragma unroll
        for (int c = piv; c < NSTEP + 2; ++c)
            pr[c] = __shfl(row[c], piv, 64);
        __builtin_amdgcn_sched_barrier(0);
        double pinv = 1.0 / pr[piv];
        double f = row[piv] * pinv;       // lanes>=20: row==0 -> f==0
        #pragma unroll
        for (int c = piv; c < NSTEP + 2; ++c) {
            double nv = row[c] - f * pr[c];
            row[c] = (t == piv) ? (pr[c] * pinv) : nv;
        }
    }
    if (t < NSTEP) { zs[0][t] = row[NSTEP]; zs[1][t] = row[NSTEP + 1]; }
    __syncthreads();

    // Phase C: per-lane LDS prefix reads -> bvec, gvec; emit C
    if (t < NHID) C[t] = (float)uv_[t];
    if (t < NSTEP) {
        const double hdt2 = 0.5 * dt * dt;
        double bacc = 0.0, gacc = 0.0;
        for (int c = 0; c <= t; ++c) {
            double ssel = hdt2 + (double)(t - c) * dt * dt;
            bacc += zs[0][c] * ssel;
            gacc += zs[1][c] * ssel;
        }
        C[32 + t] = (float)(-2.0 * dt * bacc);
        C[64 + t] = (float)((double)(t + 1) * dt - 2.0 * dt * gacc);
    }
}

// ---------------------------------------------------------------------------
// Main: out[b,k] = gp + tb*bvec[k] + gv*gvec[k], tb = x_b . u. Pure streaming.
// ---------------------------------------------------------------------------
__global__ __launch_bounds__(256) void mpc_main(
    const float* __restrict__ x, const float* __restrict__ gp,
    const float* __restrict__ gv, const float* __restrict__ C,
    float* __restrict__ out)
{
    __shared__ float xs[256 * NHID];     // 25600 B
    __shared__ float us[NHID];
    __shared__ float bs[NSTEP];
    __shared__ float gs[NSTEP];
    const int t = threadIdx.x;
    const size_t b0 = (size_t)blockIdx.x * 256;

    if (t < NHID)                us[t] = C[t];
    else if (t >= 32 && t < 52)  bs[t - 32] = C[t];
    else if (t >= 64 && t < 84)  gs[t - 64] = C[t];

    {
        const float4* xsrc = (const float4*)(x + b0 * NHID);
        float4* xdst = (float4*)xs;
        #pragma unroll
        for (int i = 0; i < 7; ++i) {
            int idx = t + 256 * i;
            if (idx < 1600) xdst[idx] = xsrc[idx];   // 6400 floats
        }
    }
    const float p = gp[b0 + t];
    const float v = gv[b0 + t];
    __syncthreads();

    const float* xr = xs + t * NHID;
    float tb = 0.0f;
    #pragma unroll
    for (int i = 0; i < NHID; ++i)
        tb = fmaf(xr[i], us[i], tb);

    float4* o4 = (float4*)(out + (b0 + t) * NSTEP);
    #pragma unroll
    for (int q = 0; q < 5; ++q) {
        float4 r;
        r.x = fmaf(tb, bs[4*q+0], fmaf(v, gs[4*q+0], p));
        r.y = fmaf(tb, bs[4*q+1], fmaf(v, gs[4*q+1], p));
        r.z = fmaf(tb, bs[4*q+2], fmaf(v, gs[4*q+2], p));
        r.w = fmaf(tb, bs[4*q+3], fmaf(v, gs[4*q+3], p));
        o4[q] = r;
    }
}

extern "C" void kernel_launch(void* const* d_in, const int* in_sizes, int n_in,
                              void* d_out, int out_size, void* d_ws, size_t ws_size,
                              hipStream_t stream) {
    const float* x  = (const float*)d_in[0];
    const float* gp = (const float*)d_in[1];
    const float* gv = (const float*)d_in[2];
    const float* Af = (const float*)d_in[3];
    const float* Lq = (const float*)d_in[4];
    float* out = (float*)d_out;
    float* C   = (float*)d_ws;            // 96 floats of scratch

    const int B = in_sizes[1];            // BATCH
    hipLaunchKernelGGL(setup_kernel, dim3(1), dim3(64), 0, stream, Af, Lq, C);
    hipLaunchKernelGGL(mpc_main, dim3(B / 256), dim3(256), 0, stream,
                       x, gp, gv, C, out);
}

// Round 5
// 90.277 us; speedup vs baseline: 1.0575x; 1.0575x over previous
//
#include <hip/hip_runtime.h>

#define NHID 25
#define NSTEP 20
#define DT_ (1.0f/60.0f)
#define EPS_ 1e-4f
#define PQ_ 5.0f
#define QV_ 200.0f
#define QA_ 1.0f

// ---------------------------------------------------------------------------
// Single fused kernel. Closed forms (HW-verified R2-R4):
//   u = Q0*Af, alpha = Af^T Q0 Af          (Q0 = Lq Lq^T + eps I)
//   Qf[r][c] = (2QA+EPS)delta + 2dt^2 sum_{rr>=max} w_rr((rr-r)(rr-c)alpha+QV)
//   phi[r] = sum_{rr>=r} w_rr (rr-r)
//   rho[r] = sum_{rr>=r} w_rr ((rr+1)(rr-r)alpha + QV)
//   [z1 z2] = Qf^{-1} [phi rho]            (register GJ, lane r owns row r)
//   bvec[k] = -2dt sum_{c<=k} z1[c](hdt2+(k-c)dt^2)
//   gvec[k] = (k+1)dt - 2dt sum_{c<=k} z2[c](hdt2+(k-c)dt^2)
//   out[b,k] = gp_b + (x_b . u)*bvec[k] + gv_b*gvec[k]
//
// R3 lesson: per-block f64 GJ serialized (2 ds_bpermute per shfl, VGPR
// pressure made the compiler interleave shfl->fma at ~120cyc each) -> 62us.
// R5 fix: all setup in f32 (threshold 0.0887 >> f32 error ~1e-3), shfl batch
// pinned with sched_barrier(0) -> ~2.5us GJ, overlapped with x staging.
// Every block recomputes setup redundantly: no cross-block handoff, no
// second launch, no coherence/deadlock risk.
// ---------------------------------------------------------------------------
__global__ __launch_bounds__(256) void mpc_fused(
    const float* __restrict__ x, const float* __restrict__ gp,
    const float* __restrict__ gv, const float* __restrict__ Af,
    const float* __restrict__ Lq, float* __restrict__ out)
{
    __shared__ float xs[256 * NHID];      // 25600 B
    __shared__ float Lqs[NHID * NHID];    // 2500 B
    __shared__ float Afs[NHID];
    __shared__ float wv_[NHID];
    __shared__ float us[NHID];
    __shared__ float alpha_s;
    __shared__ float zsh[2][NSTEP];
    __shared__ float bs[NSTEP];
    __shared__ float gs[NSTEP];

    const int t = threadIdx.x;
    const size_t b0 = (size_t)blockIdx.x * 256;
    const float dt = DT_;

    // ---- stage everything (all global loads issue up-front) ----
    if (t < NHID) Afs[t] = Af[t];
    for (int i = t; i < NHID * NHID; i += 256) Lqs[i] = Lq[i];
    {
        const float4* xsrc = (const float4*)(x + b0 * NHID);
        float4* xdst = (float4*)xs;
        #pragma unroll
        for (int i = 0; i < 7; ++i) {
            int idx = t + 256 * i;
            if (idx < 1600) xdst[idx] = xsrc[idx];    // 6400 floats
        }
    }
    const float p = gp[b0 + t];
    const float v = gv[b0 + t];
    __syncthreads();

    // ---- phase A: w = Lq^T Af ; u = Lq w + eps Af ; alpha = Af . u ----
    if (t < NHID) {
        float acc = 0.0f;
        for (int i = t; i < NHID; ++i)
            acc = fmaf(Lqs[i * NHID + t], Afs[i], acc);
        wv_[t] = acc;
    }
    __syncthreads();
    if (t < NHID) {
        float acc = EPS_ * Afs[t];
        for (int j = 0; j <= t; ++j)
            acc = fmaf(Lqs[t * NHID + j], wv_[j], acc);
        us[t] = acc;
    }
    __syncthreads();
    if (t == 0) {
        float a = 0.0f;
        for (int i = 0; i < NHID; ++i) a = fmaf(Afs[i], us[i], a);
        alpha_s = a;
    }
    __syncthreads();

    // ---- phase B + GJ: wave 0 only, registers + batched shuffles ----
    if (t < 64) {
        const float alpha = alpha_s;
        float row[NSTEP + 2];
        #pragma unroll
        for (int c = 0; c < NSTEP; ++c) {
            int m0 = (t > c) ? t : c;                 // lanes>=20: empty -> 0
            float s = 0.0f;
            for (int rr = m0; rr < NSTEP; ++rr) {
                float wr = (rr == NSTEP - 1) ? PQ_ : 1.0f;
                s = fmaf(wr, fmaf((float)(rr - t) * (float)(rr - c), alpha, QV_), s);
            }
            row[c] = 2.0f * dt * dt * s + ((t == c) ? (2.0f * QA_ + EPS_) : 0.0f);
        }
        {
            float s20 = 0.0f, s21 = 0.0f;
            for (int rr = t; rr < NSTEP; ++rr) {
                float wr = (rr == NSTEP - 1) ? PQ_ : 1.0f;
                s20 += wr * (float)(rr - t);
                s21 = fmaf(wr, fmaf((float)(rr + 1) * (float)(rr - t), alpha, QV_), s21);
            }
            row[NSTEP]     = s20;
            row[NSTEP + 1] = s21;
        }
        // Gauss-Jordan (SPD, no pivoting); batch the pivot-row shuffles and
        // pin the batch so latency is paid once per pivot, not per element.
        #pragma unroll
        for (int piv = 0; piv < NSTEP; ++piv) {
            float pr[NSTEP + 2];
            #pragma unroll
            for (int c = piv; c < NSTEP + 2; ++c)
                pr[c] = __shfl(row[c], piv, 64);
            __builtin_amdgcn_sched_barrier(0);
            float pinv = 1.0f / pr[piv];
            float f = row[piv] * pinv;                // lanes>=20: row==0 -> f==0
            #pragma unroll
            for (int c = piv; c < NSTEP + 2; ++c) {
                float nv = fmaf(-f, pr[c], row[c]);
                row[c] = (t == piv) ? (pr[c] * pinv) : nv;
            }
        }
        if (t < NSTEP) { zsh[0][t] = row[NSTEP]; zsh[1][t] = row[NSTEP + 1]; }
    }
    __syncthreads();

    // ---- phase C: bvec, gvec ----
    if (t < NSTEP) {
        const float hdt2 = 0.5f * dt * dt;
        float bacc = 0.0f, gacc = 0.0f;
        for (int c = 0; c <= t; ++c) {
            float ssel = fmaf((float)(t - c), dt * dt, hdt2);
            bacc = fmaf(zsh[0][c], ssel, bacc);
            gacc = fmaf(zsh[1][c], ssel, gacc);
        }
        bs[t] = -2.0f * dt * bacc;
        gs[t] = fmaf((float)(t + 1), dt, -2.0f * dt * gacc);
    }
    __syncthreads();

    // ---- batch epilogue: out[b,k] = p + tb*bs[k] + v*gs[k] ----
    const float* xr = xs + t * NHID;
    float tb = 0.0f;
    #pragma unroll
    for (int i = 0; i < NHID; ++i)
        tb = fmaf(xr[i], us[i], tb);

    float4* o4 = (float4*)(out + (b0 + t) * NSTEP);
    #pragma unroll
    for (int q = 0; q < 5; ++q) {
        float4 r;
        r.x = fmaf(tb, bs[4*q+0], fmaf(v, gs[4*q+0], p));
        r.y = fmaf(tb, bs[4*q+1], fmaf(v, gs[4*q+1], p));
        r.z = fmaf(tb, bs[4*q+2], fmaf(v, gs[4*q+2], p));
        r.w = fmaf(tb, bs[4*q+3], fmaf(v, gs[4*q+3], p));
        o4[q] = r;
    }
}

extern "C" void kernel_launch(void* const* d_in, const int* in_sizes, int n_in,
                              void* d_out, int out_size, void* d_ws, size_t ws_size,
                              hipStream_t stream) {
    const float* x  = (const float*)d_in[0];
    const float* gp = (const float*)d_in[1];
    const float* gv = (const float*)d_in[2];
    const float* Af = (const float*)d_in[3];
    const float* Lq = (const float*)d_in[4];
    float* out = (float*)d_out;

    const int B = in_sizes[1];            // BATCH
    hipLaunchKernelGGL(mpc_fused, dim3(B / 256), dim3(256), 0, stream,
                       x, gp, gv, Af, Lq, out);
}

// Round 6
// 86.659 us; speedup vs baseline: 1.1017x; 1.0417x over previous
//
#include <hip/hip_runtime.h>

#define NHID 25
#define NSTEP 20
#define DT_ (1.0f/60.0f)
#define EPS_ 1e-4f
#define PQ_ 5.0f
#define QV_ 200.0f
#define QA_ 1.0f
#define NAUG (NSTEP + 2)      // 22 columns: [Qf | phi | rho]
#define NEL  (NSTEP * NAUG)   // 440 elements

// ---------------------------------------------------------------------------
// Single fused kernel. Closed forms (HW-verified R2-R5):
//   u = Q0*Af, alpha = Af^T Q0 Af          (Q0 = Lq Lq^T + eps I)
//   Qf[r][c] = (2QA+EPS)delta + 2dt^2 sum_{rr>=max} w_rr((rr-r)(rr-c)alpha+QV)
//   phi[r] = sum_{rr>=r} w_rr (rr-r)
//   rho[r] = sum_{rr>=r} w_rr ((rr+1)(rr-r)alpha + QV)
//   [z1 z2] = Qf^{-1} [phi rho]
//   bvec[k] = -2dt sum_{c<=k} z1[c](hdt2+(k-c)dt^2)
//   gvec[k] = (k+1)dt - 2dt sum_{c<=k} z2[c](hdt2+(k-c)dt^2)
//   out[b,k] = gp_b + (x_b . u)*bvec[k] + gv_b*gvec[k]
//
// GJ strategy (R3/R4/R5 lesson): register+shuffle GJ ALWAYS serializes
// (~110cyc/ds_bpermute, compiler won't batch; 20x22 shfls ~ 20us). Here the
// 20x22 system lives in LDS and all 256 threads update it with 2 barriers
// per pivot; pivot row/col reads are same-address broadcasts (free). ~2.5us.
// Every block recomputes setup redundantly: no 2nd launch, no cross-block
// handoff, overlaps with other blocks' HBM streaming.
// ---------------------------------------------------------------------------
__global__ __launch_bounds__(256) void mpc_fused(
    const float* __restrict__ x, const float* __restrict__ gp,
    const float* __restrict__ gv, const float* __restrict__ Af,
    const float* __restrict__ Lq, float* __restrict__ out)
{
    __shared__ float xs[256 * NHID];       // 25600 B
    __shared__ float Lqs[NHID * NHID];     // 2500 B
    __shared__ float Afs[NHID];
    __shared__ float wv_[NHID];
    __shared__ float us[NHID];
    __shared__ float alpha_s;
    __shared__ float aug[NSTEP][NAUG + 2]; // pad stride to 24 floats
    __shared__ float bs[NSTEP];
    __shared__ float gs[NSTEP];

    const int t = threadIdx.x;
    const size_t b0 = (size_t)blockIdx.x * 256;
    const float dt = DT_;

    // ---- stage everything (all global loads issue up-front) ----
    if (t < NHID) Afs[t] = Af[t];
    for (int i = t; i < NHID * NHID; i += 256) Lqs[i] = Lq[i];
    {
        const float4* xsrc = (const float4*)(x + b0 * NHID);
        float4* xdst = (float4*)xs;
        #pragma unroll
        for (int i = 0; i < 7; ++i) {
            int idx = t + 256 * i;
            if (idx < 1600) xdst[idx] = xsrc[idx];     // 6400 floats
        }
    }
    const float p = gp[b0 + t];
    const float v = gv[b0 + t];
    __syncthreads();

    // ---- phase A: w = Lq^T Af ; u = Lq w + eps Af ; alpha = Af . u ----
    if (t < NHID) {
        float acc = 0.0f;
        for (int i = t; i < NHID; ++i)
            acc = fmaf(Lqs[i * NHID + t], Afs[i], acc);
        wv_[t] = acc;
    }
    __syncthreads();
    if (t < NHID) {
        float acc = EPS_ * Afs[t];
        for (int j = 0; j <= t; ++j)
            acc = fmaf(Lqs[t * NHID + j], wv_[j], acc);
        us[t] = acc;
    }
    __syncthreads();
    if (t == 0) {
        float a = 0.0f;
        for (int i = 0; i < NHID; ++i) a = fmaf(Afs[i], us[i], a);
        alpha_s = a;
    }
    __syncthreads();
    const float alpha = alpha_s;

    // ---- phase B: build [Qf | phi | rho], 440 elems striped over 256 thr ----
    for (int idx = t; idx < NEL; idx += 256) {
        int r = idx / NAUG, c = idx % NAUG;
        float val;
        if (c < NSTEP) {
            int m0 = (r > c) ? r : c;
            float s = 0.0f;
            for (int rr = m0; rr < NSTEP; ++rr) {
                float wr = (rr == NSTEP - 1) ? PQ_ : 1.0f;
                s = fmaf(wr, fmaf((float)(rr - r) * (float)(rr - c), alpha, QV_), s);
            }
            val = 2.0f * dt * dt * s + ((r == c) ? (2.0f * QA_ + EPS_) : 0.0f);
        } else if (c == NSTEP) {
            float s = 0.0f;
            for (int rr = r; rr < NSTEP; ++rr)
                s += ((rr == NSTEP - 1) ? PQ_ : 1.0f) * (float)(rr - r);
            val = s;
        } else {
            float s = 0.0f;
            for (int rr = r; rr < NSTEP; ++rr) {
                float wr = (rr == NSTEP - 1) ? PQ_ : 1.0f;
                s = fmaf(wr, fmaf((float)(rr + 1) * (float)(rr - r), alpha, QV_), s);
            }
            val = s;
        }
        aug[r][c] = val;
    }
    __syncthreads();

    // ---- Gauss-Jordan in LDS: 2 barriers/pivot, broadcast reads are free ----
    const int r0 = t / NAUG,        c0 = t % NAUG;          // elem 0 (t<440)
    const int r1 = (t + 256) / NAUG, c1 = (t + 256) % NAUG; // elem 1 (t<184)
    for (int piv = 0; piv < NSTEP; ++piv) {
        float app  = aug[piv][piv];                  // broadcast
        float pinv = 1.0f / app;
        float n0 = 0.0f, n1 = 0.0f;
        if (t < NEL) {
            float arc = aug[r0][c0], apc = aug[piv][c0], arp = aug[r0][piv];
            n0 = (r0 == piv) ? arc * pinv : fmaf(-arp * pinv, apc, arc);
        }
        if (t < NEL - 256) {
            float arc = aug[r1][c1], apc = aug[piv][c1], arp = aug[r1][piv];
            n1 = (r1 == piv) ? arc * pinv : fmaf(-arp * pinv, apc, arc);
        }
        __syncthreads();
        if (t < NEL)       aug[r0][c0] = n0;
        if (t < NEL - 256) aug[r1][c1] = n1;
        __syncthreads();
    }

    // ---- phase C: bvec, gvec from z1=aug[.][20], z2=aug[.][21] ----
    if (t < NSTEP) {
        const float hdt2 = 0.5f * dt * dt;
        float bacc = 0.0f, gacc = 0.0f;
        for (int c = 0; c <= t; ++c) {
            float ssel = fmaf((float)(t - c), dt * dt, hdt2);
            bacc = fmaf(aug[c][NSTEP],     ssel, bacc);
            gacc = fmaf(aug[c][NSTEP + 1], ssel, gacc);
        }
        bs[t] = -2.0f * dt * bacc;
        gs[t] = fmaf((float)(t + 1), dt, -2.0f * dt * gacc);
    }
    __syncthreads();

    // ---- batch epilogue: out[b,k] = p + tb*bs[k] + v*gs[k] ----
    const float* xr = xs + t * NHID;
    float tb = 0.0f;
    #pragma unroll
    for (int i = 0; i < NHID; ++i)
        tb = fmaf(xr[i], us[i], tb);

    float4* o4 = (float4*)(out + (b0 + t) * NSTEP);
    #pragma unroll
    for (int q = 0; q < 5; ++q) {
        float4 r;
        r.x = fmaf(tb, bs[4*q+0], fmaf(v, gs[4*q+0], p));
        r.y = fmaf(tb, bs[4*q+1], fmaf(v, gs[4*q+1], p));
        r.z = fmaf(tb, bs[4*q+2], fmaf(v, gs[4*q+2], p));
        r.w = fmaf(tb, bs[4*q+3], fmaf(v, gs[4*q+3], p));
        o4[q] = r;
    }
}

extern "C" void kernel_launch(void* const* d_in, const int* in_sizes, int n_in,
                              void* d_out, int out_size, void* d_ws, size_t ws_size,
                              hipStream_t stream) {
    const float* x  = (const float*)d_in[0];
    const float* gp = (const float*)d_in[1];
    const float* gv = (const float*)d_in[2];
    const float* Af = (const float*)d_in[3];
    const float* Lq = (const float*)d_in[4];
    float* out = (float*)d_out;

    const int B = in_sizes[1];            // BATCH
    hipLaunchKernelGGL(mpc_fused, dim3(B / 256), dim3(256), 0, stream,
                       x, gp, gv, Af, Lq, out);
}